// Round 6
// baseline (1418.308 us; speedup 1.0000x reference)
//
#include <hip/hip_runtime.h>

#define NN    48
#define DD    16
#define HH    256
#define EE    2256
#define BB    32
#define NPRED 8
#define LSTR  56
#define STP   20                     // state LDS row stride (floats), 80 B = 16B-aligned
#define ROWB  80                     // Apl row stride bytes (5x16B, bijective)
#define TMAX  7                      // packed tiles/block <= 7 (a+b<=94 -> ceil/16 sum <= 7)
#define APL_PLANE (TMAX*16*ROWB)     // 8960 B per plane

typedef __attribute__((ext_vector_type(4))) float f32x4;
typedef __attribute__((ext_vector_type(8))) short short8;

__device__ __forceinline__ float bf2f(unsigned short h) {
    union { unsigned u; float f; } v; v.u = ((unsigned)h) << 16; return v.f;
}
__device__ __forceinline__ unsigned short f2bf(float x) {
    union { float f; unsigned u; } v; v.f = x;
    unsigned r = v.u + 0x7fffu + ((v.u >> 16) & 1u);
    return (unsigned short)(r >> 16);
}

// ---------------------------------------------------------------------------
// Setup: state copy, W1 transpose, type-grouped edge lists, W2 split into
// 3 bf16 planes in MFMA B-fragment order (unchanged — verified).
// ---------------------------------------------------------------------------
__global__ __launch_bounds__(256) void k_setup(
    const float* __restrict__ time_segs,
    const float* __restrict__ edge_types,
    const float* __restrict__ W1,      // (2,32,256)
    const float* __restrict__ W2,      // (2,256,256)
    float* __restrict__ state,
    float* __restrict__ W1T,           // (2,256,32)
    unsigned short* __restrict__ W2f,  // 393216
    int* __restrict__ lists,
    int* __restrict__ counts)
{
    const int tid = blockIdx.x * 256 + threadIdx.x;   // 0..1535
    for (int i = tid; i < BB*NN*DD; i += BB*NN)
        state[i] = time_segs[i];
    for (int i = tid; i < 2*HH*32; i += BB*NN) {
        const int t = i >> 13, r = i & 8191, h = r >> 5, f = r & 31;
        W1T[i] = W1[(t*32 + f)*HH + h];
    }
    for (int i = tid; i < 2*8*16*64*8; i += BB*NN) {
        const int j  = i & 7, l = (i >> 3) & 63, nt = (i >> 9) & 15;
        const int kt = (i >> 13) & 7, t = (i >> 16) & 1;
        const int k = kt*32 + ((l >> 4) << 3) + j;
        const int n = nt*16 + (l & 15);
        const float w = W2[((size_t)t*HH + k)*HH + n];
        const unsigned short h0 = f2bf(w);  const float r1 = w  - bf2f(h0);
        const unsigned short h1 = f2bf(r1); const float r2 = r1 - bf2f(h1);
        const unsigned short h2 = f2bf(r2);
        const size_t rest = (size_t)kt*8192 + nt*512 + l*8 + j;
        W2f[(size_t)(t*3+0)*65536 + rest] = h0;
        W2f[(size_t)(t*3+1)*65536 + rest] = h1;
        W2f[(size_t)(t*3+2)*65536 + rest] = h2;
    }
    const int b = tid / NN;
    const int n = tid % NN;
    int* lst = lists + tid * LSTR;
    int c = 0;
    for (int s = 0; s < NN; ++s) {
        if (s == n) continue;
        const int e = s * 47 + (n > s ? n - 1 : n);
        if (edge_types[((size_t)b*EE + e)*3 + 1] > 0.5f) lst[c++] = s;
    }
    const int c1 = c;
    for (int s = 0; s < NN; ++s) {
        if (s == n) continue;
        const int e = s * 47 + (n > s ? n - 1 : n);
        if (edge_types[((size_t)b*EE + e)*3 + 2] > 0.5f) lst[c++] = s;
    }
    counts[tid*2 + 0] = c1;
    counts[tid*2 + 1] = c - c1;
    for (int i = c; i < LSTR; ++i) lst[i] = 0;
}

// ---------------------------------------------------------------------------
// Encoder: 512 threads (8 waves), block = 2 nodes, edges packed per type.
// Layer 1: 1 col/thread (col=tid&31) -> st reads are wave-broadcast (no
// gather conflicts), exact fp32, split to 3 bf16 planes in LDS.
// Layer 2: bf16x3 MFMA (6 products); each wave owns 2 n-tiles ->
// acc[7][2][4]=56 VGPR, peak ~110 arch VGPR -> no spills.
// ---------------------------------------------------------------------------
__global__ __launch_bounds__(512, 2) void k_enc(
    const float* __restrict__ state,
    const int*   __restrict__ lists,
    const int*   __restrict__ counts,
    const float* __restrict__ W1T,   // (2,256,32) fp32
    const float* __restrict__ b1,    // (2,256)
    const unsigned short* __restrict__ W2f,
    const float* __restrict__ b2,    // (2,256)
    float* __restrict__ node_msg)
{
    const int pair = blockIdx.x % (NN/2);
    const int b    = blockIdx.x / (NN/2);
    const int n0   = pair * 2;
    const int tid  = threadIdx.x;        // 0..511
    const int lane = tid & 63, wave = tid >> 6;   // 8 waves
    const int col  = tid & 31;           // layer-1 column within 32-slice
    const int rgrp = tid >> 5;           // 0..15 row group

    __shared__ __align__(16) float st[NN*STP];         // 3.84 KB
    __shared__ __align__(16) char  Apl[3*APL_PLANE];   // 26.9 KB
    __shared__ int lst_s[2][LSTR];
    __shared__ int rowinfo[TMAX*16];                   // src | g<<8 (g=t*2+nd, 4=pad)
    __shared__ int cnt_s[4];

    for (int i = tid; i < NN*DD; i += 512)
        st[(i >> 4)*STP + (i & 15)] = state[(size_t)b*NN*DD + i];
    for (int i = tid; i < 2*LSTR; i += 512)
        lst_s[i/LSTR][i%LSTR] = lists[(b*NN + n0 + i/LSTR)*LSTR + (i%LSTR)];
    if (tid < 4) cnt_s[tid] = counts[(b*NN + n0 + (tid>>1))*2 + (tid&1)];
    __syncthreads();

    const int c00 = cnt_s[0], c10 = cnt_s[1], c01 = cnt_s[2], c11 = cnt_s[3];
    const int tA  = c00 + c01, tB = c10 + c11;
    const int tAt = (tA + 15) >> 4, tBt = (tB + 15) >> 4;
    const int tiles = tAt + tBt;

    for (int r = tid; r < tiles*16; r += 512) {
        int g, src;
        if (r < tAt*16) {
            if (r < c00)     { src = lst_s[0][r];            g = 0; }
            else if (r < tA) { src = lst_s[1][r - c00];      g = 1; }
            else             { src = c00 ? lst_s[0][0] : lst_s[1][0]; g = 4; }
        } else {
            const int s = r - tAt*16;
            if (s < c10)     { src = lst_s[0][c00 + s];      g = 2; }
            else if (s < tB) { src = lst_s[1][c01 + s - c10]; g = 3; }
            else             { src = c10 ? lst_s[0][c00] : lst_s[1][c01]; g = 4; }
        }
        rowinfo[r] = src | (g << 8);
    }
    __syncthreads();

    f32x4 acc[TMAX][2];
    #pragma unroll
    for (int q = 0; q < TMAX; ++q) {
        acc[q][0] = (f32x4){0.f, 0.f, 0.f, 0.f};
        acc[q][1] = (f32x4){0.f, 0.f, 0.f, 0.f};
    }

    for (int kt = 0; kt < 8; ++kt) {
        const int col0 = kt*32 + col;
        // ---- layer-1 slice: exact fp32, 1 col/thread, split to 3 planes ----
        int secBase = 0;
        #pragma unroll
        for (int t = 0; t < 2; ++t) {
            const int secT = t ? tBt : tAt;
            if (secT) {
                const float* Wc = W1T + ((size_t)t*HH + col0)*32;
                float4 wa[4];
                #pragma unroll
                for (int f4 = 0; f4 < 4; ++f4) wa[f4] = ((const float4*)Wc)[f4];
                float vtA = b1[t*HH + col0], vtB = vtA;
                #pragma unroll
                for (int f4 = 0; f4 < 4; ++f4) {
                    const float4 w  = ((const float4*)(Wc + 16))[f4];
                    const float4 s0 = *(const float4*)(st + n0*STP + f4*4);
                    const float4 s1 = *(const float4*)(st + (n0+1)*STP + f4*4);
                    vtA = fmaf(s0.x,w.x, fmaf(s0.y,w.y, fmaf(s0.z,w.z, fmaf(s0.w,w.w, vtA))));
                    vtB = fmaf(s1.x,w.x, fmaf(s1.y,w.y, fmaf(s1.z,w.z, fmaf(s1.w,w.w, vtB))));
                }
                const int rend = secBase + secT*16;
                for (int r = secBase + rgrp; r < rend; r += 16) {
                    const int info = rowinfo[r];
                    const int src  = info & 255;
                    float u = (info & 256) ? vtB : vtA;
                    const float* srow = st + src*STP;
                    #pragma unroll
                    for (int f4 = 0; f4 < 4; ++f4) {
                        const float4 s4 = *(const float4*)(srow + f4*4);
                        u = fmaf(s4.x,wa[f4].x, fmaf(s4.y,wa[f4].y, fmaf(s4.z,wa[f4].z, fmaf(s4.w,wa[f4].w, u))));
                    }
                    u = fmaxf(u, 0.f);
                    const unsigned short a0 = f2bf(u);  const float e0 = u  - bf2f(a0);
                    const unsigned short a1 = f2bf(e0); const float e1 = e0 - bf2f(a1);
                    const unsigned short a2 = f2bf(e1);
                    char* p = Apl + r*ROWB + col*2;
                    *(unsigned short*)(p)               = a0;
                    *(unsigned short*)(p + APL_PLANE)   = a1;
                    *(unsigned short*)(p + 2*APL_PLANE) = a2;
                }
            }
            secBase += secT*16;
        }
        __syncthreads();

        // ---- MFMA: type-pure sections, 2 n-tiles/wave, bf16x3 (6 prod) ----
        const int abase = (lane & 15)*ROWB + (lane >> 4)*16;
        if (tAt) {
            short8 Bf[2][3];
            #pragma unroll
            for (int i = 0; i < 2; ++i)
                #pragma unroll
                for (int p = 0; p < 3; ++p)
                    Bf[i][p] = *(const short8*)(W2f + ((size_t)p*65536
                                 + (size_t)kt*8192 + (wave*2 + i)*512 + lane*8));
            #pragma unroll
            for (int q = 0; q < TMAX; ++q) {
                if (q < tAt) {
                    short8 Af[3];
                    const char* ap = Apl + q*16*ROWB + abase;
                    #pragma unroll
                    for (int p = 0; p < 3; ++p)
                        Af[p] = *(const short8*)(ap + p*APL_PLANE);
                    #pragma unroll
                    for (int i = 0; i < 2; ++i) {
                        f32x4 a = acc[q][i];
                        a = __builtin_amdgcn_mfma_f32_16x16x32_bf16(Af[2], Bf[i][0], a, 0, 0, 0);
                        a = __builtin_amdgcn_mfma_f32_16x16x32_bf16(Af[1], Bf[i][1], a, 0, 0, 0);
                        a = __builtin_amdgcn_mfma_f32_16x16x32_bf16(Af[0], Bf[i][2], a, 0, 0, 0);
                        a = __builtin_amdgcn_mfma_f32_16x16x32_bf16(Af[1], Bf[i][0], a, 0, 0, 0);
                        a = __builtin_amdgcn_mfma_f32_16x16x32_bf16(Af[0], Bf[i][1], a, 0, 0, 0);
                        a = __builtin_amdgcn_mfma_f32_16x16x32_bf16(Af[0], Bf[i][0], a, 0, 0, 0);
                        acc[q][i] = a;
                    }
                }
            }
        }
        if (tBt) {
            short8 Bf[2][3];
            #pragma unroll
            for (int i = 0; i < 2; ++i)
                #pragma unroll
                for (int p = 0; p < 3; ++p)
                    Bf[i][p] = *(const short8*)(W2f + ((size_t)(3+p)*65536
                                 + (size_t)kt*8192 + (wave*2 + i)*512 + lane*8));
            #pragma unroll
            for (int q = 0; q < TMAX; ++q) {
                if (q >= tAt && q < tiles) {
                    short8 Af[3];
                    const char* ap = Apl + q*16*ROWB + abase;
                    #pragma unroll
                    for (int p = 0; p < 3; ++p)
                        Af[p] = *(const short8*)(ap + p*APL_PLANE);
                    #pragma unroll
                    for (int i = 0; i < 2; ++i) {
                        f32x4 a = acc[q][i];
                        a = __builtin_amdgcn_mfma_f32_16x16x32_bf16(Af[2], Bf[i][0], a, 0, 0, 0);
                        a = __builtin_amdgcn_mfma_f32_16x16x32_bf16(Af[1], Bf[i][1], a, 0, 0, 0);
                        a = __builtin_amdgcn_mfma_f32_16x16x32_bf16(Af[0], Bf[i][2], a, 0, 0, 0);
                        a = __builtin_amdgcn_mfma_f32_16x16x32_bf16(Af[1], Bf[i][0], a, 0, 0, 0);
                        a = __builtin_amdgcn_mfma_f32_16x16x32_bf16(Af[0], Bf[i][1], a, 0, 0, 0);
                        a = __builtin_amdgcn_mfma_f32_16x16x32_bf16(Af[0], Bf[i][0], a, 0, 0, 0);
                        acc[q][i] = a;
                    }
                }
            }
        }
        __syncthreads();
    }

    // ---- readout: relu(acc+b2), per-row node mask, shfl-reduce, store ----
    float b2v[2][2];
    #pragma unroll
    for (int t = 0; t < 2; ++t)
        #pragma unroll
        for (int i = 0; i < 2; ++i)
            b2v[t][i] = b2[t*HH + (wave*2 + i)*16 + (lane & 15)];

    float p0[2], p1[2];
    p0[0] = p0[1] = p1[0] = p1[1] = 0.f;
    #pragma unroll
    for (int q = 0; q < TMAX; ++q) {
        if (q < tiles) {
            const bool secB = (q >= tAt);
            int gv[4];
            #pragma unroll
            for (int rr = 0; rr < 4; ++rr)
                gv[rr] = rowinfo[q*16 + (lane >> 4)*4 + rr] >> 8;
            #pragma unroll
            for (int i = 0; i < 2; ++i) {
                const float bias = secB ? b2v[1][i] : b2v[0][i];
                #pragma unroll
                for (int rr = 0; rr < 4; ++rr) {
                    const float v = fmaxf(acc[q][i][rr] + bias, 0.f);
                    const bool valid = gv[rr] < 4;
                    p0[i] += (valid && !(gv[rr] & 1)) ? v : 0.f;
                    p1[i] += (valid &&  (gv[rr] & 1)) ? v : 0.f;
                }
            }
        }
    }
    #pragma unroll
    for (int i = 0; i < 2; ++i) {
        float v0 = p0[i], v1 = p1[i];
        v0 += __shfl_xor(v0, 16); v0 += __shfl_xor(v0, 32);
        v1 += __shfl_xor(v1, 16); v1 += __shfl_xor(v1, 32);
        if ((lane >> 4) == 0) {
            node_msg[((size_t)(b*NN + n0  ))*HH + (wave*2 + i)*16 + lane] = v0;
            node_msg[((size_t)(b*NN + n0+1))*HH + (wave*2 + i)*16 + lane] = v1;
        }
    }
}

// ---------------------------------------------------------------------------
// Decoder: unchanged (passing, ~12 us/step).
// ---------------------------------------------------------------------------
__global__ __launch_bounds__(128, 3) void k_dec(
    float* __restrict__ state,
    const float* __restrict__ node_msg,
    const float* __restrict__ W1, const float* __restrict__ b1,
    const float* __restrict__ W2, const float* __restrict__ b2,
    const float* __restrict__ W3, const float* __restrict__ b3,
    float* __restrict__ out, int step)
{
    const int b    = blockIdx.x / 12;
    const int row0 = (blockIdx.x % 12) * 4;
    const int c    = threadIdx.x, c2 = c + 128;

    __shared__ float in_s[4][272];
    __shared__ float d1[4][HH];

    for (int i = threadIdx.x; i < 4*272; i += 128) {
        const int m = i / 272, k = i % 272;
        const int r = row0 + m;
        in_s[m][k] = (k < DD)
            ? state[((size_t)b*NN + r)*DD + k]
            : node_msg[((size_t)b*NN + r)*HH + (k - DD)];
    }
    __syncthreads();

    float a0[4], a1[4];
    {
        const float bb0 = b1[c], bb1 = b1[c2];
        #pragma unroll
        for (int m = 0; m < 4; ++m) { a0[m] = bb0; a1[m] = bb1; }
        #pragma unroll 2
        for (int k4 = 0; k4 < 68; ++k4) {
            const float* wr = W1 + (k4*4)*HH;
            const float w00=wr[c],      w01=wr[c2];
            const float w10=wr[HH+c],   w11=wr[HH+c2];
            const float w20=wr[2*HH+c], w21=wr[2*HH+c2];
            const float w30=wr[3*HH+c], w31=wr[3*HH+c2];
            #pragma unroll
            for (int m = 0; m < 4; ++m) {
                const float4 h = *(const float4*)&in_s[m][k4*4];
                a0[m] = fmaf(h.x,w00, fmaf(h.y,w10, fmaf(h.z,w20, fmaf(h.w,w30, a0[m]))));
                a1[m] = fmaf(h.x,w01, fmaf(h.y,w11, fmaf(h.z,w21, fmaf(h.w,w31, a1[m]))));
            }
        }
        #pragma unroll
        for (int m = 0; m < 4; ++m) {
            d1[m][c]  = fmaxf(a0[m], 0.f);
            d1[m][c2] = fmaxf(a1[m], 0.f);
        }
    }
    __syncthreads();
    {
        const float bb0 = b2[c], bb1 = b2[c2];
        #pragma unroll
        for (int m = 0; m < 4; ++m) { a0[m] = bb0; a1[m] = bb1; }
        #pragma unroll 2
        for (int k4 = 0; k4 < 64; ++k4) {
            const float* wr = W2 + (k4*4)*HH;
            const float w00=wr[c],      w01=wr[c2];
            const float w10=wr[HH+c],   w11=wr[HH+c2];
            const float w20=wr[2*HH+c], w21=wr[2*HH+c2];
            const float w30=wr[3*HH+c], w31=wr[3*HH+c2];
            #pragma unroll
            for (int m = 0; m < 4; ++m) {
                const float4 h = *(const float4*)&d1[m][k4*4];
                a0[m] = fmaf(h.x,w00, fmaf(h.y,w10, fmaf(h.z,w20, fmaf(h.w,w30, a0[m]))));
                a1[m] = fmaf(h.x,w01, fmaf(h.y,w11, fmaf(h.z,w21, fmaf(h.w,w31, a1[m]))));
            }
        }
        __syncthreads();
        #pragma unroll
        for (int m = 0; m < 4; ++m) {
            in_s[m][c]  = fmaxf(a0[m], 0.f);
            in_s[m][c2] = fmaxf(a1[m], 0.f);
        }
    }
    __syncthreads();
    if (threadIdx.x < 64) {
        const int m = threadIdx.x >> 4, cc = threadIdx.x & 15;
        float a = b3[cc];
        #pragma unroll 4
        for (int k4 = 0; k4 < 64; ++k4) {
            const float4 h = *(const float4*)&in_s[m][k4*4];
            a += h.x*W3[(k4*4+0)*16+cc] + h.y*W3[(k4*4+1)*16+cc]
               + h.z*W3[(k4*4+2)*16+cc] + h.w*W3[(k4*4+3)*16+cc];
        }
        const int r = row0 + m;
        const float v = state[((size_t)b*NN + r)*DD + cc] + a;
        state[((size_t)b*NN + r)*DD + cc] = v;
        out[(((size_t)b*NPRED + step)*NN + r)*DD + cc] = v;
    }
}

// ---------------------------------------------------------------------------
extern "C" void kernel_launch(void* const* d_in, const int* in_sizes, int n_in,
                              void* d_out, int out_size, void* d_ws, size_t ws_size,
                              hipStream_t stream)
{
    const float* time_segs  = (const float*)d_in[0];
    const float* edge_types = (const float*)d_in[1];
    const float* enc_W1 = (const float*)d_in[4];
    const float* enc_b1 = (const float*)d_in[5];
    const float* enc_W2 = (const float*)d_in[6];
    const float* enc_b2 = (const float*)d_in[7];
    const float* dec_W1 = (const float*)d_in[8];
    const float* dec_b1 = (const float*)d_in[9];
    const float* dec_W2 = (const float*)d_in[10];
    const float* dec_b2 = (const float*)d_in[11];
    const float* out_W  = (const float*)d_in[12];
    const float* out_b  = (const float*)d_in[13];
    float* out = (float*)d_out;

    float* state    = (float*)d_ws;                    // 24576 f
    float* node_msg = state + BB*NN*DD;                // 393216 f
    float* W1T      = node_msg + BB*NN*HH;             // 16384 f
    unsigned short* W2f = (unsigned short*)(W1T + 2*HH*32);   // 393216 us
    int*   lists    = (int*)(W2f + 2*3*65536);         // 86016 i
    int*   counts   = lists + BB*NN*LSTR;              // 3072 i

    k_setup<<<6, 256, 0, stream>>>(time_segs, edge_types, enc_W1, enc_W2,
                                   state, W1T, W2f, lists, counts);
    for (int stp = 0; stp < NPRED; ++stp) {
        k_enc<<<BB*(NN/2), 512, 0, stream>>>(state, lists, counts,
                                             W1T, enc_b1, W2f, enc_b2, node_msg);
        k_dec<<<BB*12, 128, 0, stream>>>(state, node_msg,
                                         dec_W1, dec_b1, dec_W2, dec_b2,
                                         out_W, out_b, out, stp);
    }
}